// Round 8
// baseline (1385.789 us; speedup 1.0000x reference)
//
#include <hip/hip_runtime.h>

#define P_N 100000
#define L_N 20000
#define T_N 8
#define DEG_N 48
#define D_N 64

// ---- workspace layout (float offsets) ----
#define W_PE_W1    0
#define W_PE_B1    64
#define W_PE_W2    128
#define W_PE_B2    4224
#define W_LE_W1    4288
#define W_LE_B1    4352
#define W_LE_W2    4416
#define W_LE_B2    8512
#define W_GRU_WIH  8576
#define W_GRU_WHH  20864
#define W_GRU_BIH  33152
#define W_GRU_BHH  33344
#define W_CELL_WIH 33536
#define W_CELL_WHH 45824
#define W_CELL_BIH 58112
#define W_CELL_BHH 58304
#define W_AM_W1    58496
#define W_AM_B1    91264
#define W_AM_W2    91392
#define W_AM_B2    107776
#define W_AM_W3    107904
#define W_AM_B3    116096
#define OFF_PS     116160                    // path_state fp32 [P,64]
#define OFF_LS     (OFF_PS + P_N*D_N)        // link_state fp32 [L,64]
#define OFF_AG     (OFF_LS + L_N*D_N)        // agg bf16 [L,512]: hi[256] + lo[256]
#define OFF_PSS    (OFF_AG + L_N*4*D_N)      // pss bf16 [P,9,64] at byte 4*OFF_PSS
#define PSS_U32    (P_N*9*D_N/2)
#define OFF_FLAG   (OFF_PSS + PSS_U32)       // dtype flag (int)
#define OFF_WIH16  (OFF_FLAG + 8)            // gru wih bf16 [192][64] (6144 dwords)
#define OFF_WHH16  (OFF_WIH16 + 6144)
#define OFF_LS16   (OFF_WHH16 + 6144)        // link_state bf16 hi [L][64] (640000 dwords)
#define OFF_LW16   (OFF_LS16 + 640000)       // link weights hi[81920]+lo[81920] shorts
#define OFF_LSLO   (OFF_LW16 + 81920)        // link_state bf16 lo [L][64]

typedef __attribute__((ext_vector_type(8))) short bf8_t;
typedef __attribute__((ext_vector_type(4))) float f4_t;
#define MFMA16(a,b,c) __builtin_amdgcn_mfma_f32_16x16x32_bf16(a,b,c,0,0,0)
#define LWLO 81920

__device__ __forceinline__ float bf2f(unsigned short u) {
    return __uint_as_float(((unsigned)u) << 16);
}
__device__ __forceinline__ unsigned short f2bf(float f) {
    unsigned u = __float_as_uint(f);
    unsigned r = u + 0x7FFFu + ((u >> 16) & 1u);
    return (unsigned short)(r >> 16);
}
__device__ __forceinline__ unsigned pk2(float a, float b) {
    return (unsigned)f2bf(a) | ((unsigned)f2bf(b) << 16);
}
__device__ __forceinline__ float fast_sig(float a) {
    return 1.0f / (1.0f + __expf(-a));
}
// tanh(a) = 2*sigmoid(2a) - 1; inf-safe at both ends
__device__ __forceinline__ float fast_tanh(float a) {
    float s = 1.0f / (1.0f + __expf(-2.0f * a));
    return fmaf(2.0f, s, -1.0f);
}

// ---- dtype detection ----
__global__ void detect_k(const unsigned short* __restrict__ traffic, int* __restrict__ flag) {
    if (threadIdx.x == 0 && blockIdx.x == 0) {
        int plausible = 0;
        for (int i = 0; i < 64; ++i) {
            unsigned short v = traffic[i];
            int ex = (v >> 7) & 0xFF;
            if (!(v & 0x8000) && ex >= 0x6F && ex <= 0x7E) plausible++;
        }
        *flag = (plausible >= 56) ? 1 : 0;
    }
}

// ---- weight -> fp32 conversion ----
struct WSrc { const void* p[22]; };

__global__ void conv_weights_k(WSrc src, float* __restrict__ dst, const int* __restrict__ flag) {
    const int sz[22]  = {64,64,4096,64, 64,64,4096,64, 12288,12288,192,192,
                         12288,12288,192,192, 32768,128,16384,128,8192,64};
    const int off[22] = {0,64,128,4224, 4288,4352,4416,8512, 8576,20864,33152,33344,
                         33536,45824,58112,58304, 58496,91264,91392,107776,107904,116096};
    int a = blockIdx.x;
    float* d = dst + off[a];
    int n = sz[a];
    if (*flag) {
        const unsigned short* s = (const unsigned short*)src.p[a];
        for (int i = threadIdx.x; i < n; i += blockDim.x) d[i] = bf2f(s[i]);
    } else {
        const float* s = (const float*)src.p[a];
        for (int i = threadIdx.x; i < n; i += blockDim.x) d[i] = s[i];
    }
}

// ---- GRU weights fp32 -> bf16 ----
__global__ void conv_gru16_k(const float* __restrict__ ws,
                             unsigned short* __restrict__ wih, unsigned short* __restrict__ whh) {
    int i = blockIdx.x * 256 + threadIdx.x;
    if (i < 12288) { wih[i] = f2bf(ws[W_GRU_WIH + i]); whh[i] = f2bf(ws[W_GRU_WHH + i]); }
}

// ---- link-side weights fp32 -> bf16 hi/lo pair ----
__global__ void conv_link16_k(const float* __restrict__ ws, unsigned short* __restrict__ lw) {
    int i = blockIdx.x * 256 + threadIdx.x;   // 0..81919
    if (i >= 81920) return;
    float v;
    if (i < 32768)      v = ws[W_AM_W1 + i];
    else if (i < 49152) v = ws[W_AM_W2 + (i - 32768)];
    else if (i < 57344) v = ws[W_AM_W3 + (i - 49152)];
    else if (i < 69632) v = ws[W_CELL_WIH + (i - 57344)];
    else                v = ws[W_CELL_WHH + (i - 69632)];
    unsigned short hi = f2bf(v);
    lw[i] = hi;
    lw[LWLO + i] = f2bf(v - bf2f(hi));
}

// ---- link_state fp32 -> bf16 hi/lo ----
__global__ void ls_to16_k(const float* __restrict__ ls, unsigned short* __restrict__ ohi,
                          unsigned short* __restrict__ olo) {
    int i = blockIdx.x * 256 + threadIdx.x;
    if (i < L_N * D_N) {
        float v = ls[i];
        unsigned short hi = f2bf(v);
        ohi[i] = hi;
        olo[i] = f2bf(v - bf2f(hi));
    }
}

// ---- scalar-input 2-layer relu MLP embed ----
__global__ __launch_bounds__(256) void embed_k(
    const void* __restrict__ inp,
    const float* __restrict__ w1, const float* __restrict__ b1,
    const float* __restrict__ w2, const float* __restrict__ b2,
    float* __restrict__ out, int N, const int* __restrict__ flag)
{
    int p = blockIdx.x * 256 + threadIdx.x;
    if (p >= N) return;
    float t = (*flag) ? bf2f(((const unsigned short*)inp)[p]) : ((const float*)inp)[p];
    float h1[64];
#pragma unroll
    for (int k = 0; k < 64; ++k) h1[k] = fmaxf(fmaf(t, w1[k], b1[k]), 0.0f);
#pragma unroll 1
    for (int j = 0; j < 64; ++j) {
        float acc = b2[j];
#pragma unroll
        for (int k = 0; k < 64; ++k) acc = fmaf(h1[k], w2[j * 64 + k], acc);
        out[p * 64 + j] = fmaxf(acc, 0.0f);
    }
}

// ---- MFMA path GRU: 4 waves cooperate on 16 paths; wave w owns dims [16w,16w+16) ----
__global__ __launch_bounds__(256, 4) void path_gru_mfma_k(
    const unsigned short* __restrict__ wih16,   // [192][64] bf16
    const unsigned short* __restrict__ whh16,
    const float* __restrict__ bih, const float* __restrict__ bhh,
    const unsigned short* __restrict__ ls16,    // [L][64] bf16
    float* __restrict__ path_state,
    const int* __restrict__ l2p, unsigned short* __restrict__ pss)
{
    __shared__ __align__(16) unsigned short xt[2][16 * 72];
    __shared__ __align__(16) unsigned short ht[2][16 * 72];
    __shared__ int lint[16][8];
    __shared__ int lmaskA[16];

    const int tid = threadIdx.x;
    const int w = tid >> 6;          // wave = dim-slice
    const int L = tid & 63;
    const int col = L & 15;
    const int quad = L >> 4;
    const int p0 = blockIdx.x * 16;
    const int gpath = tid >> 4;      // block-wide gather role: path 0..15
    const int gseg = tid & 15;       // 8-byte segment 0..15

    // stage l2p rows + validity masks
    if (tid < 16) {
        const int4* r4 = (const int4*)(l2p + (p0 + tid) * 8);
        int4 a = r4[0], b = r4[1];
        lint[tid][0] = a.x; lint[tid][1] = a.y; lint[tid][2] = a.z; lint[tid][3] = a.w;
        lint[tid][4] = b.x; lint[tid][5] = b.y; lint[tid][6] = b.z; lint[tid][7] = b.w;
        lmaskA[tid] = (a.x >= 0) | ((a.y >= 0) << 1) | ((a.z >= 0) << 2) | ((a.w >= 0) << 3)
                    | ((b.x >= 0) << 4) | ((b.y >= 0) << 5) | ((b.z >= 0) << 6) | ((b.w >= 0) << 7);
    }

    // weight B-frags for slice w: r-tile w, z-tile 4+w, n-tile 8+w
    bf8_t BIr[2], BHr[2], BIz[2], BHz[2], BIn[2], BHn[2];
#pragma unroll
    for (int f = 0; f < 2; ++f) {
        int orr = ((w) * 16 + col) * 64 + f * 32 + quad * 8;
        int oz  = ((4 + w) * 16 + col) * 64 + f * 32 + quad * 8;
        int on  = ((8 + w) * 16 + col) * 64 + f * 32 + quad * 8;
        BIr[f] = *(const bf8_t*)(wih16 + orr);  BHr[f] = *(const bf8_t*)(whh16 + orr);
        BIz[f] = *(const bf8_t*)(wih16 + oz);   BHz[f] = *(const bf8_t*)(whh16 + oz);
        BIn[f] = *(const bf8_t*)(wih16 + on);   BHn[f] = *(const bf8_t*)(whh16 + on);
    }
    const float bR  = bih[w * 16 + col] + bhh[w * 16 + col];
    const float bZ  = bih[64 + w * 16 + col] + bhh[64 + w * 16 + col];
    const float bIN = bih[128 + w * 16 + col];
    const float bHN = bhh[128 + w * 16 + col];

    // h0 slice (fp32, D-layout)
    float hf[4];
#pragma unroll
    for (int r = 0; r < 4; ++r)
        hf[r] = path_state[(size_t)(p0 + quad * 4 + r) * 64 + w * 16 + col];
#pragma unroll
    for (int r = 0; r < 4; ++r)
        ht[0][(quad * 4 + r) * 72 + w * 16 + col] = f2bf(hf[r]);

    __syncthreads();

    unsigned pm[4];
#pragma unroll
    for (int r = 0; r < 4; ++r) pm[r] = (unsigned)lmaskA[quad * 4 + r];
    const unsigned gm = (unsigned)lmaskA[gpath];

    // gather x0
    {
        int li = lint[gpath][0];
        uint2 v; v.x = 0u; v.y = 0u;
        if (li >= 0) v = *(const uint2*)(ls16 + (size_t)li * 64 + gseg * 4);
        *(uint2*)(&xt[0][gpath * 72 + gseg * 4]) = v;
    }
    __syncthreads();

#pragma unroll
    for (int t = 0; t < T_N; ++t) {
        const int cur = t & 1, nxt = (t + 1) & 1;
        bf8_t xA0 = *(const bf8_t*)(&xt[cur][col * 72 + quad * 8]);
        bf8_t xA1 = *(const bf8_t*)(&xt[cur][col * 72 + 32 + quad * 8]);
        bf8_t hA0 = *(const bf8_t*)(&ht[cur][col * 72 + quad * 8]);
        bf8_t hA1 = *(const bf8_t*)(&ht[cur][col * 72 + 32 + quad * 8]);

        // pss row t (cooperative, masked by valid(t-1); row 0 unmasked)
        // NOTE: ternary (not bitwise |) — avoids compile-time gm>>-1 poison at t==0
        {
            uint2 hv = *(const uint2*)(&ht[cur][gpath * 72 + gseg * 4]);
            int keep = (t == 0) ? 1 : (int)((gm >> (t - 1)) & 1);
            if (!keep) { hv.x = 0u; hv.y = 0u; }
            *(uint2*)(pss + (size_t)(p0 + gpath) * 576 + t * 64 + gseg * 4) = hv;
        }
        // prefetch x_{t+1}
        uint2 pf; pf.x = 0u; pf.y = 0u;
        if (t < T_N - 1) {
            int li = lint[gpath][t + 1];
            if (li >= 0) pf = *(const uint2*)(ls16 + (size_t)li * 64 + gseg * 4);
        }

        f4_t aR = {bR, bR, bR, bR};
        f4_t aZ = {bZ, bZ, bZ, bZ};
        f4_t aI = {bIN, bIN, bIN, bIN};
        f4_t aH = {bHN, bHN, bHN, bHN};
        aR = MFMA16(xA0, BIr[0], aR); aR = MFMA16(xA1, BIr[1], aR);
        aR = MFMA16(hA0, BHr[0], aR); aR = MFMA16(hA1, BHr[1], aR);
        aZ = MFMA16(xA0, BIz[0], aZ); aZ = MFMA16(xA1, BIz[1], aZ);
        aZ = MFMA16(hA0, BHz[0], aZ); aZ = MFMA16(hA1, BHz[1], aZ);
        aI = MFMA16(xA0, BIn[0], aI); aI = MFMA16(xA1, BIn[1], aI);
        aH = MFMA16(hA0, BHn[0], aH); aH = MFMA16(hA1, BHn[1], aH);

        if (t < T_N - 1)
            *(uint2*)(&xt[nxt][gpath * 72 + gseg * 4]) = pf;

        // gate math: 4 values/lane
#pragma unroll
        for (int r = 0; r < 4; ++r) {
            float rr = fast_sig(aR[r]);
            float zz = fast_sig(aZ[r]);
            float nn = fast_tanh(fmaf(rr, aH[r], aI[r]));
            float hb = hf[r];
            float hv = fmaf(zz, hb - nn, nn);     // (1-z)n + z h
            hf[r] = ((pm[r] >> t) & 1) ? hv : hb;
        }
#pragma unroll
        for (int r = 0; r < 4; ++r)
            ht[nxt][(quad * 4 + r) * 72 + w * 16 + col] = f2bf(hf[r]);
        __syncthreads();
    }

    // epilogue: h8 lives in ht[0]; pss row 8 masked by valid(7)
    {
        uint2 hv = *(const uint2*)(&ht[0][gpath * 72 + gseg * 4]);
        if (!((gm >> 7) & 1)) { hv.x = 0u; hv.y = 0u; }
        *(uint2*)(pss + (size_t)(p0 + gpath) * 576 + 8 * 64 + gseg * 4) = hv;
    }
#pragma unroll
    for (int r = 0; r < 4; ++r)
        path_state[(size_t)(p0 + quad * 4 + r) * 64 + w * 16 + col] = hf[r];
}

// ---- link aggregation: 4 links/block, fully-unrolled branchless gather ----
__global__ __launch_bounds__(256) void link_agg_k(
    const int* __restrict__ p2l, const unsigned short* __restrict__ pss,
    unsigned short* __restrict__ agg16)
{
    const int l = blockIdx.x * 4 + (threadIdx.x >> 6);
    const int lane = threadIdx.x & 63;
    if (l >= L_N) return;
    const int* row = p2l + l * 96;
    float vmin = INFINITY, vmax = -INFINITY, vsum = 0.0f;
    int cnt = 0;
#pragma unroll
    for (int d0 = 0; d0 < DEG_N; d0 += 8) {
        float v[8]; int val[8];
#pragma unroll
        for (int j = 0; j < 8; ++j) {
            int pid = row[(d0 + j) * 2];
            int pos = row[(d0 + j) * 2 + 1];
            val[j] = pid >= 0;
            size_t idx = val[j] ? ((size_t)pid * 9 + pos) : 0;
            v[j] = bf2f(pss[idx * 64 + lane]);
        }
#pragma unroll
        for (int j = 0; j < 8; ++j) {
            vmin = fminf(vmin, val[j] ? v[j] : INFINITY);
            vmax = fmaxf(vmax, val[j] ? v[j] : -INFINITY);
            vsum += val[j] ? v[j] : 0.0f;
            cnt += val[j];
        }
    }
    float mean = vsum / (float)max(cnt, 1);
    unsigned short* orow = agg16 + (size_t)l * 512;
    float vals[4] = {vmin, vmax, vsum, mean};
#pragma unroll
    for (int c = 0; c < 4; ++c) {
        unsigned short hi = f2bf(vals[c]);
        orow[c * 64 + lane] = hi;
        orow[256 + c * 64 + lane] = f2bf(vals[c] - bf2f(hi));
    }
}

// ---- MFMA link update, hi/lo compensated: MLP(256->128->128->64) + GRU cell ----
__global__ __launch_bounds__(256, 2) void link_upd_mfma_k(
    const unsigned short* __restrict__ lw,
    const float* __restrict__ b1, const float* __restrict__ b2, const float* __restrict__ b3,
    const float* __restrict__ cbih, const float* __restrict__ cbhh,
    const unsigned short* __restrict__ agg16,
    float* __restrict__ link_state,
    unsigned short* __restrict__ lshi, unsigned short* __restrict__ lslo)
{
    __shared__ __align__(16) unsigned short tile[4][2 * 16 * 136];
    const int tid = threadIdx.x;
    const int wv = tid >> 6;
    const int L = tid & 63;
    const int col = L & 15;
    const int quad = L >> 4;
    const int l0 = blockIdx.x * 64 + wv * 16;
    const int mlink = min(l0 + col, L_N - 1);
    unsigned short* tlhi = &tile[wv][0];
    unsigned short* tllo = &tile[wv][16 * 136];

    const unsigned short* w1b = lw;            // [128][256]
    const unsigned short* w2b = lw + 32768;    // [128][128]
    const unsigned short* w3b = lw + 49152;    // [64][128]
    const unsigned short* cih = lw + 57344;    // [192][64]
    const unsigned short* chh = lw + 69632;    // [192][64]

    // phase 1
    {
        bf8_t Ah[8], Al[8];
#pragma unroll
        for (int f = 0; f < 8; ++f) {
            Ah[f] = *(const bf8_t*)(agg16 + (size_t)mlink * 512 + f * 32 + quad * 8);
            Al[f] = *(const bf8_t*)(agg16 + (size_t)mlink * 512 + 256 + f * 32 + quad * 8);
        }
#pragma unroll
        for (int nt = 0; nt < 8; ++nt) {
            float bb = b1[nt * 16 + col];
            f4_t acc = {bb, bb, bb, bb};
#pragma unroll
            for (int f = 0; f < 8; ++f) {
                size_t o = (size_t)(nt * 16 + col) * 256 + f * 32 + quad * 8;
                bf8_t Bh = *(const bf8_t*)(w1b + o);
                bf8_t Bl = *(const bf8_t*)(w1b + LWLO + o);
                acc = MFMA16(Ah[f], Bh, acc);
                acc = MFMA16(Ah[f], Bl, acc);
                acc = MFMA16(Al[f], Bh, acc);
            }
#pragma unroll
            for (int r = 0; r < 4; ++r) {
                float v = fmaxf(acc[r], 0.0f);
                unsigned short hi = f2bf(v);
                tlhi[(quad * 4 + r) * 136 + nt * 16 + col] = hi;
                tllo[(quad * 4 + r) * 136 + nt * 16 + col] = f2bf(v - bf2f(hi));
            }
        }
    }
    // phase 2
    {
        bf8_t Ah[4], Al[4];
#pragma unroll
        for (int f = 0; f < 4; ++f) {
            Ah[f] = *(const bf8_t*)(tlhi + col * 136 + f * 32 + quad * 8);
            Al[f] = *(const bf8_t*)(tllo + col * 136 + f * 32 + quad * 8);
        }
        float vv[8][4];
#pragma unroll
        for (int nt = 0; nt < 8; ++nt) {
            float bb = b2[nt * 16 + col];
            f4_t acc = {bb, bb, bb, bb};
#pragma unroll
            for (int f = 0; f < 4; ++f) {
                size_t o = (size_t)(nt * 16 + col) * 128 + f * 32 + quad * 8;
                bf8_t Bh = *(const bf8_t*)(w2b + o);
                bf8_t Bl = *(const bf8_t*)(w2b + LWLO + o);
                acc = MFMA16(Ah[f], Bh, acc);
                acc = MFMA16(Ah[f], Bl, acc);
                acc = MFMA16(Al[f], Bh, acc);
            }
#pragma unroll
            for (int r = 0; r < 4; ++r) vv[nt][r] = fmaxf(acc[r], 0.0f);
        }
#pragma unroll
        for (int nt = 0; nt < 8; ++nt)
#pragma unroll
            for (int r = 0; r < 4; ++r) {
                unsigned short hi = f2bf(vv[nt][r]);
                tlhi[(quad * 4 + r) * 136 + nt * 16 + col] = hi;
                tllo[(quad * 4 + r) * 136 + nt * 16 + col] = f2bf(vv[nt][r] - bf2f(hi));
            }
    }
    // phase 3
    {
        bf8_t Ah[4], Al[4];
#pragma unroll
        for (int f = 0; f < 4; ++f) {
            Ah[f] = *(const bf8_t*)(tlhi + col * 136 + f * 32 + quad * 8);
            Al[f] = *(const bf8_t*)(tllo + col * 136 + f * 32 + quad * 8);
        }
        float vv[4][4];
#pragma unroll
        for (int nt = 0; nt < 4; ++nt) {
            float bb = b3[nt * 16 + col];
            f4_t acc = {bb, bb, bb, bb};
#pragma unroll
            for (int f = 0; f < 4; ++f) {
                size_t o = (size_t)(nt * 16 + col) * 128 + f * 32 + quad * 8;
                bf8_t Bh = *(const bf8_t*)(w3b + o);
                bf8_t Bl = *(const bf8_t*)(w3b + LWLO + o);
                acc = MFMA16(Ah[f], Bh, acc);
                acc = MFMA16(Ah[f], Bl, acc);
                acc = MFMA16(Al[f], Bh, acc);
            }
#pragma unroll
            for (int r = 0; r < 4; ++r) vv[nt][r] = fmaxf(acc[r], 0.0f);
        }
#pragma unroll
        for (int nt = 0; nt < 4; ++nt)
#pragma unroll
            for (int r = 0; r < 4; ++r) {
                unsigned short hi = f2bf(vv[nt][r]);
                tlhi[(quad * 4 + r) * 136 + nt * 16 + col] = hi;
                tllo[(quad * 4 + r) * 136 + nt * 16 + col] = f2bf(vv[nt][r] - bf2f(hi));
            }
    }
    // GRU cell
    bf8_t xAh[2], xAl[2], hAh[2], hAl[2];
#pragma unroll
    for (int f = 0; f < 2; ++f) {
        xAh[f] = *(const bf8_t*)(tlhi + col * 136 + f * 32 + quad * 8);
        xAl[f] = *(const bf8_t*)(tllo + col * 136 + f * 32 + quad * 8);
        hAh[f] = *(const bf8_t*)(lshi + (size_t)mlink * 64 + f * 32 + quad * 8);
        hAl[f] = *(const bf8_t*)(lslo + (size_t)mlink * 64 + f * 32 + quad * 8);
    }
    float hf[16];
#pragma unroll
    for (int nt = 0; nt < 4; ++nt)
#pragma unroll
        for (int r = 0; r < 4; ++r) {
            int ml = min(l0 + quad * 4 + r, L_N - 1);
            hf[nt * 4 + r] = link_state[(size_t)ml * 64 + nt * 16 + col];
        }
    f4_t aRZ[8], aIN[4], aHN[4];
#pragma unroll
    for (int nt = 0; nt < 8; ++nt) {
        float bb = cbih[nt * 16 + col] + cbhh[nt * 16 + col];
        aRZ[nt][0] = bb; aRZ[nt][1] = bb; aRZ[nt][2] = bb; aRZ[nt][3] = bb;
    }
#pragma unroll
    for (int nt = 0; nt < 4; ++nt) {
        float bi = cbih[128 + nt * 16 + col], bh = cbhh[128 + nt * 16 + col];
        aIN[nt][0] = bi; aIN[nt][1] = bi; aIN[nt][2] = bi; aIN[nt][3] = bi;
        aHN[nt][0] = bh; aHN[nt][1] = bh; aHN[nt][2] = bh; aHN[nt][3] = bh;
    }
#pragma unroll
    for (int nt = 0; nt < 8; ++nt) {
#pragma unroll
        for (int f = 0; f < 2; ++f) {
            size_t o = (size_t)(nt * 16 + col) * 64 + f * 32 + quad * 8;
            bf8_t Bih = *(const bf8_t*)(cih + o);
            bf8_t Bil = *(const bf8_t*)(cih + LWLO + o);
            bf8_t Bhh = *(const bf8_t*)(chh + o);
            bf8_t Bhl = *(const bf8_t*)(chh + LWLO + o);
            aRZ[nt] = MFMA16(xAh[f], Bih, aRZ[nt]);
            aRZ[nt] = MFMA16(xAh[f], Bil, aRZ[nt]);
            aRZ[nt] = MFMA16(xAl[f], Bih, aRZ[nt]);
            aRZ[nt] = MFMA16(hAh[f], Bhh, aRZ[nt]);
            aRZ[nt] = MFMA16(hAh[f], Bhl, aRZ[nt]);
            aRZ[nt] = MFMA16(hAl[f], Bhh, aRZ[nt]);
        }
    }
#pragma unroll
    for (int nt = 0; nt < 4; ++nt) {
#pragma unroll
        for (int f = 0; f < 2; ++f) {
            size_t o = (size_t)((8 + nt) * 16 + col) * 64 + f * 32 + quad * 8;
            bf8_t Bih = *(const bf8_t*)(cih + o);
            bf8_t Bil = *(const bf8_t*)(cih + LWLO + o);
            bf8_t Bhh = *(const bf8_t*)(chh + o);
            bf8_t Bhl = *(const bf8_t*)(chh + LWLO + o);
            aIN[nt] = MFMA16(xAh[f], Bih, aIN[nt]);
            aIN[nt] = MFMA16(xAh[f], Bil, aIN[nt]);
            aIN[nt] = MFMA16(xAl[f], Bih, aIN[nt]);
            aHN[nt] = MFMA16(hAh[f], Bhh, aHN[nt]);
            aHN[nt] = MFMA16(hAh[f], Bhl, aHN[nt]);
            aHN[nt] = MFMA16(hAl[f], Bhh, aHN[nt]);
        }
    }
#pragma unroll
    for (int nt = 0; nt < 4; ++nt)
#pragma unroll
        for (int r = 0; r < 4; ++r) {
            int mrow = l0 + quad * 4 + r;
            float rr = fast_sig(aRZ[nt][r]);
            float zz = fast_sig(aRZ[nt + 4][r]);
            float nn = fast_tanh(fmaf(rr, aHN[nt][r], aIN[nt][r]));
            float hb = hf[nt * 4 + r];
            float hv = fmaf(zz, hb - nn, nn);
            if (mrow < L_N) {
                link_state[(size_t)mrow * 64 + nt * 16 + col] = hv;
                unsigned short hi = f2bf(hv);
                lshi[(size_t)mrow * 64 + nt * 16 + col] = hi;
                lslo[(size_t)mrow * 64 + nt * 16 + col] = f2bf(hv - bf2f(hi));
            }
        }
}

// ---- final fp32 -> (bf16 | f32) output ----
__global__ void final_out_k(const float* __restrict__ ps, const float* __restrict__ ls,
                            void* __restrict__ out, const int* __restrict__ flag)
{
    int i = blockIdx.x * 256 + threadIdx.x;
    int e = i * 2;
    float a, b;
    if (e < P_N * D_N) { a = ps[e]; b = ps[e + 1]; }
    else               { a = ls[e - P_N * D_N]; b = ls[e - P_N * D_N + 1]; }
    if (*flag) {
        ((unsigned*)out)[i] = pk2(a, b);
    } else {
        float2 v; v.x = a; v.y = b;
        ((float2*)out)[i] = v;
    }
}

extern "C" void kernel_launch(void* const* d_in, const int* in_sizes, int n_in,
                              void* d_out, int out_size, void* d_ws, size_t ws_size,
                              hipStream_t stream)
{
    const int* l2p = (const int*)d_in[2];
    const int* p2l = (const int*)d_in[3];
    float* ws = (float*)d_ws;
    int* flag = (int*)(ws + OFF_FLAG);
    unsigned short* wih16 = (unsigned short*)(ws + OFF_WIH16);
    unsigned short* whh16 = (unsigned short*)(ws + OFF_WHH16);
    unsigned short* lshi  = (unsigned short*)(ws + OFF_LS16);
    unsigned short* lslo  = (unsigned short*)(ws + OFF_LSLO);
    unsigned short* lw16  = (unsigned short*)(ws + OFF_LW16);
    unsigned short* agg16 = (unsigned short*)(ws + OFF_AG);
    unsigned short* pss   = (unsigned short*)(ws + OFF_PSS);

    detect_k<<<1, 64, 0, stream>>>((const unsigned short*)d_in[0], flag);

    WSrc srcs;
    for (int i = 0; i < 22; ++i) srcs.p[i] = d_in[4 + i];
    conv_weights_k<<<22, 256, 0, stream>>>(srcs, ws, flag);
    conv_gru16_k<<<48, 256, 0, stream>>>(ws, wih16, whh16);
    conv_link16_k<<<320, 256, 0, stream>>>(ws, lw16);

    embed_k<<<(P_N + 255) / 256, 256, 0, stream>>>(d_in[0], ws + W_PE_W1, ws + W_PE_B1,
                                                   ws + W_PE_W2, ws + W_PE_B2, ws + OFF_PS, P_N, flag);
    embed_k<<<(L_N + 255) / 256, 256, 0, stream>>>(d_in[1], ws + W_LE_W1, ws + W_LE_B1,
                                                   ws + W_LE_W2, ws + W_LE_B2, ws + OFF_LS, L_N, flag);
    ls_to16_k<<<(L_N * D_N + 255) / 256, 256, 0, stream>>>(ws + OFF_LS, lshi, lslo);

    for (int it = 0; it < 4; ++it) {
        path_gru_mfma_k<<<P_N / 16, 256, 0, stream>>>(
            wih16, whh16, ws + W_GRU_BIH, ws + W_GRU_BHH,
            lshi, ws + OFF_PS, l2p, pss);
        link_agg_k<<<(L_N + 3) / 4, 256, 0, stream>>>(p2l, pss, agg16);
        link_upd_mfma_k<<<(L_N + 63) / 64, 256, 0, stream>>>(
            lw16, ws + W_AM_B1, ws + W_AM_B2, ws + W_AM_B3,
            ws + W_CELL_BIH, ws + W_CELL_BHH,
            agg16, ws + OFF_LS, lshi, lslo);
    }
    final_out_k<<<(P_N * D_N + L_N * D_N) / 512, 256, 0, stream>>>(
        ws + OFF_PS, ws + OFF_LS, d_out, flag);
}

// Round 9
// 1239.827 us; speedup vs baseline: 1.1177x; 1.1177x over previous
//
#include <hip/hip_runtime.h>

#define P_N 100000
#define L_N 20000
#define T_N 8
#define DEG_N 48
#define D_N 64

// ---- workspace layout (float offsets) ----
#define W_PE_W1    0
#define W_PE_B1    64
#define W_PE_W2    128
#define W_PE_B2    4224
#define W_LE_W1    4288
#define W_LE_B1    4352
#define W_LE_W2    4416
#define W_LE_B2    8512
#define W_GRU_WIH  8576
#define W_GRU_WHH  20864
#define W_GRU_BIH  33152
#define W_GRU_BHH  33344
#define W_CELL_WIH 33536
#define W_CELL_WHH 45824
#define W_CELL_BIH 58112
#define W_CELL_BHH 58304
#define W_AM_W1    58496
#define W_AM_B1    91264
#define W_AM_W2    91392
#define W_AM_B2    107776
#define W_AM_W3    107904
#define W_AM_B3    116096
#define OFF_PS     116160                    // path_state fp32 [P,64]
#define OFF_LS     (OFF_PS + P_N*D_N)        // link_state fp32 [L,64]
#define OFF_AG     (OFF_LS + L_N*D_N)        // agg bf16 [L,512]: hi[256] + lo[256]
#define OFF_PSS    (OFF_AG + L_N*4*D_N)      // pss bf16 [P,9,64] at byte 4*OFF_PSS
#define PSS_U32    (P_N*9*D_N/2)
#define OFF_FLAG   (OFF_PSS + PSS_U32)       // dtype flag (int)
#define OFF_WIH16  (OFF_FLAG + 8)            // gru wih bf16 [192][64] (6144 dwords)
#define OFF_WHH16  (OFF_WIH16 + 6144)
#define OFF_LS16   (OFF_WHH16 + 6144)        // link_state bf16 hi [L][64] (640000 dwords)
#define OFF_LW16   (OFF_LS16 + 640000)       // link weights hi[81920]+lo[81920] shorts
#define OFF_LSLO   (OFF_LW16 + 81920)        // link_state bf16 lo [L][64]

typedef __attribute__((ext_vector_type(8))) short bf8_t;
typedef __attribute__((ext_vector_type(4))) float f4_t;
#define MFMA16(a,b,c) __builtin_amdgcn_mfma_f32_16x16x32_bf16(a,b,c,0,0,0)
#define LWLO 81920

__device__ __forceinline__ float bf2f(unsigned short u) {
    return __uint_as_float(((unsigned)u) << 16);
}
__device__ __forceinline__ unsigned short f2bf(float f) {
    unsigned u = __float_as_uint(f);
    unsigned r = u + 0x7FFFu + ((u >> 16) & 1u);
    return (unsigned short)(r >> 16);
}
__device__ __forceinline__ unsigned pk2(float a, float b) {
    return (unsigned)f2bf(a) | ((unsigned)f2bf(b) << 16);
}
__device__ __forceinline__ float fast_sig(float a) {
    return 1.0f / (1.0f + __expf(-a));
}
// tanh(a) = 2*sigmoid(2a) - 1; inf-safe at both ends
__device__ __forceinline__ float fast_tanh(float a) {
    float s = 1.0f / (1.0f + __expf(-2.0f * a));
    return fmaf(2.0f, s, -1.0f);
}

// ---- dtype detection ----
__global__ void detect_k(const unsigned short* __restrict__ traffic, int* __restrict__ flag) {
    if (threadIdx.x == 0 && blockIdx.x == 0) {
        int plausible = 0;
        for (int i = 0; i < 64; ++i) {
            unsigned short v = traffic[i];
            int ex = (v >> 7) & 0xFF;
            if (!(v & 0x8000) && ex >= 0x6F && ex <= 0x7E) plausible++;
        }
        *flag = (plausible >= 56) ? 1 : 0;
    }
}

// ---- weight -> fp32 conversion ----
struct WSrc { const void* p[22]; };

__global__ void conv_weights_k(WSrc src, float* __restrict__ dst, const int* __restrict__ flag) {
    const int sz[22]  = {64,64,4096,64, 64,64,4096,64, 12288,12288,192,192,
                         12288,12288,192,192, 32768,128,16384,128,8192,64};
    const int off[22] = {0,64,128,4224, 4288,4352,4416,8512, 8576,20864,33152,33344,
                         33536,45824,58112,58304, 58496,91264,91392,107776,107904,116096};
    int a = blockIdx.x;
    float* d = dst + off[a];
    int n = sz[a];
    if (*flag) {
        const unsigned short* s = (const unsigned short*)src.p[a];
        for (int i = threadIdx.x; i < n; i += blockDim.x) d[i] = bf2f(s[i]);
    } else {
        const float* s = (const float*)src.p[a];
        for (int i = threadIdx.x; i < n; i += blockDim.x) d[i] = s[i];
    }
}

// ---- GRU weights fp32 -> bf16 ----
__global__ void conv_gru16_k(const float* __restrict__ ws,
                             unsigned short* __restrict__ wih, unsigned short* __restrict__ whh) {
    int i = blockIdx.x * 256 + threadIdx.x;
    if (i < 12288) { wih[i] = f2bf(ws[W_GRU_WIH + i]); whh[i] = f2bf(ws[W_GRU_WHH + i]); }
}

// ---- link-side weights fp32 -> bf16 hi/lo pair ----
__global__ void conv_link16_k(const float* __restrict__ ws, unsigned short* __restrict__ lw) {
    int i = blockIdx.x * 256 + threadIdx.x;   // 0..81919
    if (i >= 81920) return;
    float v;
    if (i < 32768)      v = ws[W_AM_W1 + i];
    else if (i < 49152) v = ws[W_AM_W2 + (i - 32768)];
    else if (i < 57344) v = ws[W_AM_W3 + (i - 49152)];
    else if (i < 69632) v = ws[W_CELL_WIH + (i - 57344)];
    else                v = ws[W_CELL_WHH + (i - 69632)];
    unsigned short hi = f2bf(v);
    lw[i] = hi;
    lw[LWLO + i] = f2bf(v - bf2f(hi));
}

// ---- link_state fp32 -> bf16 hi/lo ----
__global__ void ls_to16_k(const float* __restrict__ ls, unsigned short* __restrict__ ohi,
                          unsigned short* __restrict__ olo) {
    int i = blockIdx.x * 256 + threadIdx.x;
    if (i < L_N * D_N) {
        float v = ls[i];
        unsigned short hi = f2bf(v);
        ohi[i] = hi;
        olo[i] = f2bf(v - bf2f(hi));
    }
}

// ---- pre-zero invalid pss rows (validity is iteration-independent) ----
// row (p, t+1) is zero for all iterations iff l2p[p*8+t] < 0; row 0 always valid.
__global__ void pss_zero_k(const int* __restrict__ l2p, unsigned short* __restrict__ pss) {
    int i = blockIdx.x * 256 + threadIdx.x;    // over P_N*8
    if (i >= P_N * 8) return;
    int p = i >> 3, t = i & 7;
    if (l2p[i] >= 0) return;
    uint4 z; z.x = z.y = z.z = z.w = 0u;
    uint4* row = (uint4*)(pss + (size_t)p * 576 + (t + 1) * 64);
#pragma unroll
    for (int g = 0; g < 8; ++g) row[g] = z;
}

// ---- scalar-input 2-layer relu MLP embed ----
__global__ __launch_bounds__(256) void embed_k(
    const void* __restrict__ inp,
    const float* __restrict__ w1, const float* __restrict__ b1,
    const float* __restrict__ w2, const float* __restrict__ b2,
    float* __restrict__ out, int N, const int* __restrict__ flag)
{
    int p = blockIdx.x * 256 + threadIdx.x;
    if (p >= N) return;
    float t = (*flag) ? bf2f(((const unsigned short*)inp)[p]) : ((const float*)inp)[p];
    float h1[64];
#pragma unroll
    for (int k = 0; k < 64; ++k) h1[k] = fmaxf(fmaf(t, w1[k], b1[k]), 0.0f);
#pragma unroll 1
    for (int j = 0; j < 64; ++j) {
        float acc = b2[j];
#pragma unroll
        for (int k = 0; k < 64; ++k) acc = fmaf(h1[k], w2[j * 64 + k], acc);
        out[p * 64 + j] = fmaxf(acc, 0.0f);
    }
}

// ---- MFMA path GRU: 4 waves cooperate on 16 paths; wave w owns dims [16w,16w+16) ----
// Valid rows only are stored (invalid rows pre-zeroed by pss_zero_k).
__global__ __launch_bounds__(256, 3) void path_gru_mfma_k(
    const unsigned short* __restrict__ wih16,   // [192][64] bf16
    const unsigned short* __restrict__ whh16,
    const float* __restrict__ bih, const float* __restrict__ bhh,
    const unsigned short* __restrict__ ls16,    // [L][64] bf16
    float* __restrict__ path_state,
    const int* __restrict__ l2p, unsigned short* __restrict__ pss)
{
    __shared__ __align__(16) unsigned short xt[2][16 * 72];
    __shared__ __align__(16) unsigned short ht[2][16 * 72];
    __shared__ int lint[16][8];
    __shared__ int lmaskA[16];

    const int tid = threadIdx.x;
    const int w = tid >> 6;          // wave = dim-slice
    const int L = tid & 63;
    const int col = L & 15;
    const int quad = L >> 4;
    const int p0 = blockIdx.x * 16;
    const int gpath = tid >> 4;      // block-wide gather role: path 0..15
    const int gseg = tid & 15;       // 8-byte segment 0..15

    // stage l2p rows + validity masks
    if (tid < 16) {
        const int4* r4 = (const int4*)(l2p + (p0 + tid) * 8);
        int4 a = r4[0], b = r4[1];
        lint[tid][0] = a.x; lint[tid][1] = a.y; lint[tid][2] = a.z; lint[tid][3] = a.w;
        lint[tid][4] = b.x; lint[tid][5] = b.y; lint[tid][6] = b.z; lint[tid][7] = b.w;
        lmaskA[tid] = (a.x >= 0) | ((a.y >= 0) << 1) | ((a.z >= 0) << 2) | ((a.w >= 0) << 3)
                    | ((b.x >= 0) << 4) | ((b.y >= 0) << 5) | ((b.z >= 0) << 6) | ((b.w >= 0) << 7);
    }

    // weight B-frags for slice w: r-tile w, z-tile 4+w, n-tile 8+w
    bf8_t BIr[2], BHr[2], BIz[2], BHz[2], BIn[2], BHn[2];
#pragma unroll
    for (int f = 0; f < 2; ++f) {
        int orr = ((w) * 16 + col) * 64 + f * 32 + quad * 8;
        int oz  = ((4 + w) * 16 + col) * 64 + f * 32 + quad * 8;
        int on  = ((8 + w) * 16 + col) * 64 + f * 32 + quad * 8;
        BIr[f] = *(const bf8_t*)(wih16 + orr);  BHr[f] = *(const bf8_t*)(whh16 + orr);
        BIz[f] = *(const bf8_t*)(wih16 + oz);   BHz[f] = *(const bf8_t*)(whh16 + oz);
        BIn[f] = *(const bf8_t*)(wih16 + on);   BHn[f] = *(const bf8_t*)(whh16 + on);
    }
    const float bR  = bih[w * 16 + col] + bhh[w * 16 + col];
    const float bZ  = bih[64 + w * 16 + col] + bhh[64 + w * 16 + col];
    const float bIN = bih[128 + w * 16 + col];
    const float bHN = bhh[128 + w * 16 + col];

    // h0 slice (fp32, D-layout)
    float hf[4];
#pragma unroll
    for (int r = 0; r < 4; ++r)
        hf[r] = path_state[(size_t)(p0 + quad * 4 + r) * 64 + w * 16 + col];
#pragma unroll
    for (int r = 0; r < 4; ++r)
        ht[0][(quad * 4 + r) * 72 + w * 16 + col] = f2bf(hf[r]);

    __syncthreads();

    unsigned pm[4];
#pragma unroll
    for (int r = 0; r < 4; ++r) pm[r] = (unsigned)lmaskA[quad * 4 + r];
    const unsigned gm = (unsigned)lmaskA[gpath];

    // gather x0
    {
        int li = lint[gpath][0];
        uint2 v; v.x = 0u; v.y = 0u;
        if (li >= 0) v = *(const uint2*)(ls16 + (size_t)li * 64 + gseg * 4);
        *(uint2*)(&xt[0][gpath * 72 + gseg * 4]) = v;
    }
    __syncthreads();

#pragma unroll 2
    for (int t = 0; t < T_N; ++t) {
        const int cur = t & 1, nxt = (t + 1) & 1;
        bf8_t xA0 = *(const bf8_t*)(&xt[cur][col * 72 + quad * 8]);
        bf8_t xA1 = *(const bf8_t*)(&xt[cur][col * 72 + 32 + quad * 8]);
        bf8_t hA0 = *(const bf8_t*)(&ht[cur][col * 72 + quad * 8]);
        bf8_t hA1 = *(const bf8_t*)(&ht[cur][col * 72 + 32 + quad * 8]);

        // pss row t: store only if valid (invalid rows pre-zeroed).
        // ternary (not bitwise |) — avoids compile-time gm>>-1 poison at t==0
        {
            int keep = (t == 0) ? 1 : (int)((gm >> (t - 1)) & 1);
            if (keep) {
                uint2 hv = *(const uint2*)(&ht[cur][gpath * 72 + gseg * 4]);
                *(uint2*)(pss + (size_t)(p0 + gpath) * 576 + t * 64 + gseg * 4) = hv;
            }
        }
        // prefetch x_{t+1}
        uint2 pf; pf.x = 0u; pf.y = 0u;
        if (t < T_N - 1) {
            int li = lint[gpath][t + 1];
            if (li >= 0) pf = *(const uint2*)(ls16 + (size_t)li * 64 + gseg * 4);
        }

        f4_t aR = {bR, bR, bR, bR};
        f4_t aZ = {bZ, bZ, bZ, bZ};
        f4_t aI = {bIN, bIN, bIN, bIN};
        f4_t aH = {bHN, bHN, bHN, bHN};
        aR = MFMA16(xA0, BIr[0], aR); aR = MFMA16(xA1, BIr[1], aR);
        aR = MFMA16(hA0, BHr[0], aR); aR = MFMA16(hA1, BHr[1], aR);
        aZ = MFMA16(xA0, BIz[0], aZ); aZ = MFMA16(xA1, BIz[1], aZ);
        aZ = MFMA16(hA0, BHz[0], aZ); aZ = MFMA16(hA1, BHz[1], aZ);
        aI = MFMA16(xA0, BIn[0], aI); aI = MFMA16(xA1, BIn[1], aI);
        aH = MFMA16(hA0, BHn[0], aH); aH = MFMA16(hA1, BHn[1], aH);

        if (t < T_N - 1)
            *(uint2*)(&xt[nxt][gpath * 72 + gseg * 4]) = pf;

        // gate math: 4 values/lane
#pragma unroll
        for (int r = 0; r < 4; ++r) {
            float rr = fast_sig(aR[r]);
            float zz = fast_sig(aZ[r]);
            float nn = fast_tanh(fmaf(rr, aH[r], aI[r]));
            float hb = hf[r];
            float hv = fmaf(zz, hb - nn, nn);     // (1-z)n + z h
            hf[r] = ((pm[r] >> t) & 1) ? hv : hb;
        }
#pragma unroll
        for (int r = 0; r < 4; ++r)
            ht[nxt][(quad * 4 + r) * 72 + w * 16 + col] = f2bf(hf[r]);
        __syncthreads();
    }

    // epilogue: h8 lives in ht[0]; row 8 stored only if valid(7)
    if ((gm >> 7) & 1) {
        uint2 hv = *(const uint2*)(&ht[0][gpath * 72 + gseg * 4]);
        *(uint2*)(pss + (size_t)(p0 + gpath) * 576 + 8 * 64 + gseg * 4) = hv;
    }
#pragma unroll
    for (int r = 0; r < 4; ++r)
        path_state[(size_t)(p0 + quad * 4 + r) * 64 + w * 16 + col] = hf[r];
}

// ---- link aggregation (R6 form): one wave per link, serial branchy loop ----
__global__ __launch_bounds__(64) void link_agg_k(
    const int* __restrict__ p2l, const unsigned short* __restrict__ pss,
    unsigned short* __restrict__ agg16)
{
    const int l = blockIdx.x;
    const int lane = threadIdx.x;
    float vmin = INFINITY, vmax = -INFINITY, vsum = 0.0f;
    int cnt = 0;
#pragma unroll 1
    for (int d = 0; d < DEG_N; ++d) {
        int pid = p2l[l * 96 + d * 2];
        int pos = p2l[l * 96 + d * 2 + 1];
        if (pid >= 0) {
            float v = bf2f(pss[((size_t)pid * 9 + pos) * 64 + lane]);
            vmin = fminf(vmin, v); vmax = fmaxf(vmax, v); vsum += v; cnt++;
        }
    }
    float mean = vsum / (float)max(cnt, 1);
    unsigned short* row = agg16 + (size_t)l * 512;
    float vals[4] = {vmin, vmax, vsum, mean};
#pragma unroll
    for (int c = 0; c < 4; ++c) {
        unsigned short hi = f2bf(vals[c]);
        row[c * 64 + lane] = hi;
        row[256 + c * 64 + lane] = f2bf(vals[c] - bf2f(hi));
    }
}

// ---- MFMA link update, hi/lo compensated: MLP(256->128->128->64) + GRU cell ----
__global__ __launch_bounds__(256, 2) void link_upd_mfma_k(
    const unsigned short* __restrict__ lw,
    const float* __restrict__ b1, const float* __restrict__ b2, const float* __restrict__ b3,
    const float* __restrict__ cbih, const float* __restrict__ cbhh,
    const unsigned short* __restrict__ agg16,
    float* __restrict__ link_state,
    unsigned short* __restrict__ lshi, unsigned short* __restrict__ lslo)
{
    __shared__ __align__(16) unsigned short tile[4][2 * 16 * 136];
    const int tid = threadIdx.x;
    const int wv = tid >> 6;
    const int L = tid & 63;
    const int col = L & 15;
    const int quad = L >> 4;
    const int l0 = blockIdx.x * 64 + wv * 16;
    const int mlink = min(l0 + col, L_N - 1);
    unsigned short* tlhi = &tile[wv][0];
    unsigned short* tllo = &tile[wv][16 * 136];

    const unsigned short* w1b = lw;            // [128][256]
    const unsigned short* w2b = lw + 32768;    // [128][128]
    const unsigned short* w3b = lw + 49152;    // [64][128]
    const unsigned short* cih = lw + 57344;    // [192][64]
    const unsigned short* chh = lw + 69632;    // [192][64]

    // phase 1
    {
        bf8_t Ah[8], Al[8];
#pragma unroll
        for (int f = 0; f < 8; ++f) {
            Ah[f] = *(const bf8_t*)(agg16 + (size_t)mlink * 512 + f * 32 + quad * 8);
            Al[f] = *(const bf8_t*)(agg16 + (size_t)mlink * 512 + 256 + f * 32 + quad * 8);
        }
#pragma unroll
        for (int nt = 0; nt < 8; ++nt) {
            float bb = b1[nt * 16 + col];
            f4_t acc = {bb, bb, bb, bb};
#pragma unroll
            for (int f = 0; f < 8; ++f) {
                size_t o = (size_t)(nt * 16 + col) * 256 + f * 32 + quad * 8;
                bf8_t Bh = *(const bf8_t*)(w1b + o);
                bf8_t Bl = *(const bf8_t*)(w1b + LWLO + o);
                acc = MFMA16(Ah[f], Bh, acc);
                acc = MFMA16(Ah[f], Bl, acc);
                acc = MFMA16(Al[f], Bh, acc);
            }
#pragma unroll
            for (int r = 0; r < 4; ++r) {
                float v = fmaxf(acc[r], 0.0f);
                unsigned short hi = f2bf(v);
                tlhi[(quad * 4 + r) * 136 + nt * 16 + col] = hi;
                tllo[(quad * 4 + r) * 136 + nt * 16 + col] = f2bf(v - bf2f(hi));
            }
        }
    }
    // phase 2
    {
        bf8_t Ah[4], Al[4];
#pragma unroll
        for (int f = 0; f < 4; ++f) {
            Ah[f] = *(const bf8_t*)(tlhi + col * 136 + f * 32 + quad * 8);
            Al[f] = *(const bf8_t*)(tllo + col * 136 + f * 32 + quad * 8);
        }
        float vv[8][4];
#pragma unroll
        for (int nt = 0; nt < 8; ++nt) {
            float bb = b2[nt * 16 + col];
            f4_t acc = {bb, bb, bb, bb};
#pragma unroll
            for (int f = 0; f < 4; ++f) {
                size_t o = (size_t)(nt * 16 + col) * 128 + f * 32 + quad * 8;
                bf8_t Bh = *(const bf8_t*)(w2b + o);
                bf8_t Bl = *(const bf8_t*)(w2b + LWLO + o);
                acc = MFMA16(Ah[f], Bh, acc);
                acc = MFMA16(Ah[f], Bl, acc);
                acc = MFMA16(Al[f], Bh, acc);
            }
#pragma unroll
            for (int r = 0; r < 4; ++r) vv[nt][r] = fmaxf(acc[r], 0.0f);
        }
#pragma unroll
        for (int nt = 0; nt < 8; ++nt)
#pragma unroll
            for (int r = 0; r < 4; ++r) {
                unsigned short hi = f2bf(vv[nt][r]);
                tlhi[(quad * 4 + r) * 136 + nt * 16 + col] = hi;
                tllo[(quad * 4 + r) * 136 + nt * 16 + col] = f2bf(vv[nt][r] - bf2f(hi));
            }
    }
    // phase 3
    {
        bf8_t Ah[4], Al[4];
#pragma unroll
        for (int f = 0; f < 4; ++f) {
            Ah[f] = *(const bf8_t*)(tlhi + col * 136 + f * 32 + quad * 8);
            Al[f] = *(const bf8_t*)(tllo + col * 136 + f * 32 + quad * 8);
        }
        float vv[4][4];
#pragma unroll
        for (int nt = 0; nt < 4; ++nt) {
            float bb = b3[nt * 16 + col];
            f4_t acc = {bb, bb, bb, bb};
#pragma unroll
            for (int f = 0; f < 4; ++f) {
                size_t o = (size_t)(nt * 16 + col) * 128 + f * 32 + quad * 8;
                bf8_t Bh = *(const bf8_t*)(w3b + o);
                bf8_t Bl = *(const bf8_t*)(w3b + LWLO + o);
                acc = MFMA16(Ah[f], Bh, acc);
                acc = MFMA16(Ah[f], Bl, acc);
                acc = MFMA16(Al[f], Bh, acc);
            }
#pragma unroll
            for (int r = 0; r < 4; ++r) vv[nt][r] = fmaxf(acc[r], 0.0f);
        }
#pragma unroll
        for (int nt = 0; nt < 4; ++nt)
#pragma unroll
            for (int r = 0; r < 4; ++r) {
                unsigned short hi = f2bf(vv[nt][r]);
                tlhi[(quad * 4 + r) * 136 + nt * 16 + col] = hi;
                tllo[(quad * 4 + r) * 136 + nt * 16 + col] = f2bf(vv[nt][r] - bf2f(hi));
            }
    }
    // GRU cell
    bf8_t xAh[2], xAl[2], hAh[2], hAl[2];
#pragma unroll
    for (int f = 0; f < 2; ++f) {
        xAh[f] = *(const bf8_t*)(tlhi + col * 136 + f * 32 + quad * 8);
        xAl[f] = *(const bf8_t*)(tllo + col * 136 + f * 32 + quad * 8);
        hAh[f] = *(const bf8_t*)(lshi + (size_t)mlink * 64 + f * 32 + quad * 8);
        hAl[f] = *(const bf8_t*)(lslo + (size_t)mlink * 64 + f * 32 + quad * 8);
    }
    float hf[16];
#pragma unroll
    for (int nt = 0; nt < 4; ++nt)
#pragma unroll
        for (int r = 0; r < 4; ++r) {
            int ml = min(l0 + quad * 4 + r, L_N - 1);
            hf[nt * 4 + r] = link_state[(size_t)ml * 64 + nt * 16 + col];
        }
    f4_t aRZ[8], aIN[4], aHN[4];
#pragma unroll
    for (int nt = 0; nt < 8; ++nt) {
        float bb = cbih[nt * 16 + col] + cbhh[nt * 16 + col];
        aRZ[nt][0] = bb; aRZ[nt][1] = bb; aRZ[nt][2] = bb; aRZ[nt][3] = bb;
    }
#pragma unroll
    for (int nt = 0; nt < 4; ++nt) {
        float bi = cbih[128 + nt * 16 + col], bh = cbhh[128 + nt * 16 + col];
        aIN[nt][0] = bi; aIN[nt][1] = bi; aIN[nt][2] = bi; aIN[nt][3] = bi;
        aHN[nt][0] = bh; aHN[nt][1] = bh; aHN[nt][2] = bh; aHN[nt][3] = bh;
    }
#pragma unroll
    for (int nt = 0; nt < 8; ++nt) {
#pragma unroll
        for (int f = 0; f < 2; ++f) {
            size_t o = (size_t)(nt * 16 + col) * 64 + f * 32 + quad * 8;
            bf8_t Bih = *(const bf8_t*)(cih + o);
            bf8_t Bil = *(const bf8_t*)(cih + LWLO + o);
            bf8_t Bhh = *(const bf8_t*)(chh + o);
            bf8_t Bhl = *(const bf8_t*)(chh + LWLO + o);
            aRZ[nt] = MFMA16(xAh[f], Bih, aRZ[nt]);
            aRZ[nt] = MFMA16(xAh[f], Bil, aRZ[nt]);
            aRZ[nt] = MFMA16(xAl[f], Bih, aRZ[nt]);
            aRZ[nt] = MFMA16(hAh[f], Bhh, aRZ[nt]);
            aRZ[nt] = MFMA16(hAh[f], Bhl, aRZ[nt]);
            aRZ[nt] = MFMA16(hAl[f], Bhh, aRZ[nt]);
        }
    }
#pragma unroll
    for (int nt = 0; nt < 4; ++nt) {
#pragma unroll
        for (int f = 0; f < 2; ++f) {
            size_t o = (size_t)((8 + nt) * 16 + col) * 64 + f * 32 + quad * 8;
            bf8_t Bih = *(const bf8_t*)(cih + o);
            bf8_t Bil = *(const bf8_t*)(cih + LWLO + o);
            bf8_t Bhh = *(const bf8_t*)(chh + o);
            bf8_t Bhl = *(const bf8_t*)(chh + LWLO + o);
            aIN[nt] = MFMA16(xAh[f], Bih, aIN[nt]);
            aIN[nt] = MFMA16(xAh[f], Bil, aIN[nt]);
            aIN[nt] = MFMA16(xAl[f], Bih, aIN[nt]);
            aHN[nt] = MFMA16(hAh[f], Bhh, aHN[nt]);
            aHN[nt] = MFMA16(hAh[f], Bhl, aHN[nt]);
            aHN[nt] = MFMA16(hAl[f], Bhh, aHN[nt]);
        }
    }
#pragma unroll
    for (int nt = 0; nt < 4; ++nt)
#pragma unroll
        for (int r = 0; r < 4; ++r) {
            int mrow = l0 + quad * 4 + r;
            float rr = fast_sig(aRZ[nt][r]);
            float zz = fast_sig(aRZ[nt + 4][r]);
            float nn = fast_tanh(fmaf(rr, aHN[nt][r], aIN[nt][r]));
            float hb = hf[nt * 4 + r];
            float hv = fmaf(zz, hb - nn, nn);
            if (mrow < L_N) {
                link_state[(size_t)mrow * 64 + nt * 16 + col] = hv;
                unsigned short hi = f2bf(hv);
                lshi[(size_t)mrow * 64 + nt * 16 + col] = hi;
                lslo[(size_t)mrow * 64 + nt * 16 + col] = f2bf(hv - bf2f(hi));
            }
        }
}

// ---- final fp32 -> (bf16 | f32) output ----
__global__ void final_out_k(const float* __restrict__ ps, const float* __restrict__ ls,
                            void* __restrict__ out, const int* __restrict__ flag)
{
    int i = blockIdx.x * 256 + threadIdx.x;
    int e = i * 2;
    float a, b;
    if (e < P_N * D_N) { a = ps[e]; b = ps[e + 1]; }
    else               { a = ls[e - P_N * D_N]; b = ls[e - P_N * D_N + 1]; }
    if (*flag) {
        ((unsigned*)out)[i] = pk2(a, b);
    } else {
        float2 v; v.x = a; v.y = b;
        ((float2*)out)[i] = v;
    }
}

extern "C" void kernel_launch(void* const* d_in, const int* in_sizes, int n_in,
                              void* d_out, int out_size, void* d_ws, size_t ws_size,
                              hipStream_t stream)
{
    const int* l2p = (const int*)d_in[2];
    const int* p2l = (const int*)d_in[3];
    float* ws = (float*)d_ws;
    int* flag = (int*)(ws + OFF_FLAG);
    unsigned short* wih16 = (unsigned short*)(ws + OFF_WIH16);
    unsigned short* whh16 = (unsigned short*)(ws + OFF_WHH16);
    unsigned short* lshi  = (unsigned short*)(ws + OFF_LS16);
    unsigned short* lslo  = (unsigned short*)(ws + OFF_LSLO);
    unsigned short* lw16  = (unsigned short*)(ws + OFF_LW16);
    unsigned short* agg16 = (unsigned short*)(ws + OFF_AG);
    unsigned short* pss   = (unsigned short*)(ws + OFF_PSS);

    detect_k<<<1, 64, 0, stream>>>((const unsigned short*)d_in[0], flag);

    WSrc srcs;
    for (int i = 0; i < 22; ++i) srcs.p[i] = d_in[4 + i];
    conv_weights_k<<<22, 256, 0, stream>>>(srcs, ws, flag);
    conv_gru16_k<<<48, 256, 0, stream>>>(ws, wih16, whh16);
    conv_link16_k<<<320, 256, 0, stream>>>(ws, lw16);
    pss_zero_k<<<(P_N * 8 + 255) / 256, 256, 0, stream>>>(l2p, pss);

    embed_k<<<(P_N + 255) / 256, 256, 0, stream>>>(d_in[0], ws + W_PE_W1, ws + W_PE_B1,
                                                   ws + W_PE_W2, ws + W_PE_B2, ws + OFF_PS, P_N, flag);
    embed_k<<<(L_N + 255) / 256, 256, 0, stream>>>(d_in[1], ws + W_LE_W1, ws + W_LE_B1,
                                                   ws + W_LE_W2, ws + W_LE_B2, ws + OFF_LS, L_N, flag);
    ls_to16_k<<<(L_N * D_N + 255) / 256, 256, 0, stream>>>(ws + OFF_LS, lshi, lslo);

    for (int it = 0; it < 4; ++it) {
        path_gru_mfma_k<<<P_N / 16, 256, 0, stream>>>(
            wih16, whh16, ws + W_GRU_BIH, ws + W_GRU_BHH,
            lshi, ws + OFF_PS, l2p, pss);
        link_agg_k<<<L_N, 64, 0, stream>>>(p2l, pss, agg16);
        link_upd_mfma_k<<<(L_N + 63) / 64, 256, 0, stream>>>(
            lw16, ws + W_AM_B1, ws + W_AM_B2, ws + W_AM_B3,
            ws + W_CELL_BIH, ws + W_CELL_BHH,
            agg16, ws + OFF_LS, lshi, lslo);
    }
    final_out_k<<<(P_N * D_N + L_N * D_N) / 512, 256, 0, stream>>>(
        ws + OFF_PS, ws + OFF_LS, d_out, flag);
}

// Round 10
// 1103.538 us; speedup vs baseline: 1.2558x; 1.1235x over previous
//
#include <hip/hip_runtime.h>

#define P_N 100000
#define L_N 20000
#define T_N 8
#define DEG_N 48
#define D_N 64

// ---- workspace layout (float offsets) ----
#define W_PE_W1    0
#define W_PE_B1    64
#define W_PE_W2    128
#define W_PE_B2    4224
#define W_LE_W1    4288
#define W_LE_B1    4352
#define W_LE_W2    4416
#define W_LE_B2    8512
#define W_GRU_WIH  8576
#define W_GRU_WHH  20864
#define W_GRU_BIH  33152
#define W_GRU_BHH  33344
#define W_CELL_WIH 33536
#define W_CELL_WHH 45824
#define W_CELL_BIH 58112
#define W_CELL_BHH 58304
#define W_AM_W1    58496
#define W_AM_B1    91264
#define W_AM_W2    91392
#define W_AM_B2    107776
#define W_AM_W3    107904
#define W_AM_B3    116096
#define OFF_PS     116160                    // path_state fp32 [P,64]
#define OFF_LS     (OFF_PS + P_N*D_N)        // link_state fp32 [L,64]
#define OFF_AG     (OFF_LS + L_N*D_N)        // agg bf16 [L,512]: hi[256] + lo[256]
#define OFF_PSS    (OFF_AG + L_N*4*D_N)      // pss bf16 [P,9,64] at byte 4*OFF_PSS
#define PSS_U32    (P_N*9*D_N/2)
#define OFF_FLAG   (OFF_PSS + PSS_U32)       // dtype flag (int)
#define OFF_WIH16  (OFF_FLAG + 8)            // gru wih bf16 [192][64] (6144 dwords)
#define OFF_WHH16  (OFF_WIH16 + 6144)
#define OFF_LS16   (OFF_WHH16 + 6144)        // link_state bf16 hi [L][64] (640000 dwords)
#define OFF_LW16   (OFF_LS16 + 640000)       // link weights hi[81920]+lo[81920] shorts
#define OFF_LSLO   (OFF_LW16 + 81920)        // link_state bf16 lo [L][64]

typedef __attribute__((ext_vector_type(8))) short bf8_t;
typedef __attribute__((ext_vector_type(4))) float f4_t;
#define MFMA16(a,b,c) __builtin_amdgcn_mfma_f32_16x16x32_bf16(a,b,c,0,0,0)
#define LWLO 81920

__device__ __forceinline__ float bf2f(unsigned short u) {
    return __uint_as_float(((unsigned)u) << 16);
}
__device__ __forceinline__ unsigned short f2bf(float f) {
    unsigned u = __float_as_uint(f);
    unsigned r = u + 0x7FFFu + ((u >> 16) & 1u);
    return (unsigned short)(r >> 16);
}
__device__ __forceinline__ unsigned pk2(float a, float b) {
    return (unsigned)f2bf(a) | ((unsigned)f2bf(b) << 16);
}
// single-instruction hw rcp (v_rcp_f32, <=1 ulp) — avoids ~11-instr IEEE divide
__device__ __forceinline__ float fast_sig(float a) {
    return __builtin_amdgcn_rcpf(1.0f + __expf(-a));
}
// tanh(a) = 2*sigmoid(2a) - 1; inf-safe at both ends
__device__ __forceinline__ float fast_tanh(float a) {
    float s = __builtin_amdgcn_rcpf(1.0f + __expf(-2.0f * a));
    return fmaf(2.0f, s, -1.0f);
}

// ---- dtype detection ----
__global__ void detect_k(const unsigned short* __restrict__ traffic, int* __restrict__ flag) {
    if (threadIdx.x == 0 && blockIdx.x == 0) {
        int plausible = 0;
        for (int i = 0; i < 64; ++i) {
            unsigned short v = traffic[i];
            int ex = (v >> 7) & 0xFF;
            if (!(v & 0x8000) && ex >= 0x6F && ex <= 0x7E) plausible++;
        }
        *flag = (plausible >= 56) ? 1 : 0;
    }
}

// ---- weight -> fp32 conversion ----
struct WSrc { const void* p[22]; };

__global__ void conv_weights_k(WSrc src, float* __restrict__ dst, const int* __restrict__ flag) {
    const int sz[22]  = {64,64,4096,64, 64,64,4096,64, 12288,12288,192,192,
                         12288,12288,192,192, 32768,128,16384,128,8192,64};
    const int off[22] = {0,64,128,4224, 4288,4352,4416,8512, 8576,20864,33152,33344,
                         33536,45824,58112,58304, 58496,91264,91392,107776,107904,116096};
    int a = blockIdx.x;
    float* d = dst + off[a];
    int n = sz[a];
    if (*flag) {
        const unsigned short* s = (const unsigned short*)src.p[a];
        for (int i = threadIdx.x; i < n; i += blockDim.x) d[i] = bf2f(s[i]);
    } else {
        const float* s = (const float*)src.p[a];
        for (int i = threadIdx.x; i < n; i += blockDim.x) d[i] = s[i];
    }
}

// ---- GRU weights fp32 -> bf16 ----
__global__ void conv_gru16_k(const float* __restrict__ ws,
                             unsigned short* __restrict__ wih, unsigned short* __restrict__ whh) {
    int i = blockIdx.x * 256 + threadIdx.x;
    if (i < 12288) { wih[i] = f2bf(ws[W_GRU_WIH + i]); whh[i] = f2bf(ws[W_GRU_WHH + i]); }
}

// ---- link-side weights fp32 -> bf16 hi/lo pair ----
__global__ void conv_link16_k(const float* __restrict__ ws, unsigned short* __restrict__ lw) {
    int i = blockIdx.x * 256 + threadIdx.x;   // 0..81919
    if (i >= 81920) return;
    float v;
    if (i < 32768)      v = ws[W_AM_W1 + i];
    else if (i < 49152) v = ws[W_AM_W2 + (i - 32768)];
    else if (i < 57344) v = ws[W_AM_W3 + (i - 49152)];
    else if (i < 69632) v = ws[W_CELL_WIH + (i - 57344)];
    else                v = ws[W_CELL_WHH + (i - 69632)];
    unsigned short hi = f2bf(v);
    lw[i] = hi;
    lw[LWLO + i] = f2bf(v - bf2f(hi));
}

// ---- link_state fp32 -> bf16 hi/lo ----
__global__ void ls_to16_k(const float* __restrict__ ls, unsigned short* __restrict__ ohi,
                          unsigned short* __restrict__ olo) {
    int i = blockIdx.x * 256 + threadIdx.x;
    if (i < L_N * D_N) {
        float v = ls[i];
        unsigned short hi = f2bf(v);
        ohi[i] = hi;
        olo[i] = f2bf(v - bf2f(hi));
    }
}

// ---- scalar-input 2-layer relu MLP embed ----
__global__ __launch_bounds__(256) void embed_k(
    const void* __restrict__ inp,
    const float* __restrict__ w1, const float* __restrict__ b1,
    const float* __restrict__ w2, const float* __restrict__ b2,
    float* __restrict__ out, int N, const int* __restrict__ flag)
{
    int p = blockIdx.x * 256 + threadIdx.x;
    if (p >= N) return;
    float t = (*flag) ? bf2f(((const unsigned short*)inp)[p]) : ((const float*)inp)[p];
    float h1[64];
#pragma unroll
    for (int k = 0; k < 64; ++k) h1[k] = fmaxf(fmaf(t, w1[k], b1[k]), 0.0f);
#pragma unroll 1
    for (int j = 0; j < 64; ++j) {
        float acc = b2[j];
#pragma unroll
        for (int k = 0; k < 64; ++k) acc = fmaf(h1[k], w2[j * 64 + k], acc);
        out[p * 64 + j] = fmaxf(acc, 0.0f);
    }
}

// ---- MFMA path GRU: 4 waves cooperate on 16 paths; wave w owns dims [16w,16w+16) ----
__global__ __launch_bounds__(256, 3) void path_gru_mfma_k(
    const unsigned short* __restrict__ wih16,   // [192][64] bf16
    const unsigned short* __restrict__ whh16,
    const float* __restrict__ bih, const float* __restrict__ bhh,
    const unsigned short* __restrict__ ls16,    // [L][64] bf16
    float* __restrict__ path_state,
    const int* __restrict__ l2p, unsigned short* __restrict__ pss)
{
    __shared__ __align__(16) unsigned short xt[2][16 * 72];
    __shared__ __align__(16) unsigned short ht[2][16 * 72];
    __shared__ int lint[16][8];
    __shared__ int lmaskA[16];

    const int tid = threadIdx.x;
    const int w = tid >> 6;          // wave = dim-slice
    const int L = tid & 63;
    const int col = L & 15;
    const int quad = L >> 4;
    const int p0 = blockIdx.x * 16;
    const int gpath = tid >> 4;      // block-wide gather role: path 0..15
    const int gseg = tid & 15;       // 8-byte segment 0..15

    // stage l2p rows + validity masks
    if (tid < 16) {
        const int4* r4 = (const int4*)(l2p + (p0 + tid) * 8);
        int4 a = r4[0], b = r4[1];
        lint[tid][0] = a.x; lint[tid][1] = a.y; lint[tid][2] = a.z; lint[tid][3] = a.w;
        lint[tid][4] = b.x; lint[tid][5] = b.y; lint[tid][6] = b.z; lint[tid][7] = b.w;
        lmaskA[tid] = (a.x >= 0) | ((a.y >= 0) << 1) | ((a.z >= 0) << 2) | ((a.w >= 0) << 3)
                    | ((b.x >= 0) << 4) | ((b.y >= 0) << 5) | ((b.z >= 0) << 6) | ((b.w >= 0) << 7);
    }

    // weight B-frags for slice w: r-tile w, z-tile 4+w, n-tile 8+w
    bf8_t BIr[2], BHr[2], BIz[2], BHz[2], BIn[2], BHn[2];
#pragma unroll
    for (int f = 0; f < 2; ++f) {
        int orr = ((w) * 16 + col) * 64 + f * 32 + quad * 8;
        int oz  = ((4 + w) * 16 + col) * 64 + f * 32 + quad * 8;
        int on  = ((8 + w) * 16 + col) * 64 + f * 32 + quad * 8;
        BIr[f] = *(const bf8_t*)(wih16 + orr);  BHr[f] = *(const bf8_t*)(whh16 + orr);
        BIz[f] = *(const bf8_t*)(wih16 + oz);   BHz[f] = *(const bf8_t*)(whh16 + oz);
        BIn[f] = *(const bf8_t*)(wih16 + on);   BHn[f] = *(const bf8_t*)(whh16 + on);
    }
    const float bR  = bih[w * 16 + col] + bhh[w * 16 + col];
    const float bZ  = bih[64 + w * 16 + col] + bhh[64 + w * 16 + col];
    const float bIN = bih[128 + w * 16 + col];
    const float bHN = bhh[128 + w * 16 + col];

    // h0 slice (fp32, D-layout)
    float hf[4];
#pragma unroll
    for (int r = 0; r < 4; ++r)
        hf[r] = path_state[(size_t)(p0 + quad * 4 + r) * 64 + w * 16 + col];
#pragma unroll
    for (int r = 0; r < 4; ++r)
        ht[0][(quad * 4 + r) * 72 + w * 16 + col] = f2bf(hf[r]);

    __syncthreads();

    unsigned pm[4];
#pragma unroll
    for (int r = 0; r < 4; ++r) pm[r] = (unsigned)lmaskA[quad * 4 + r];
    const unsigned gm = (unsigned)lmaskA[gpath];

    // gather x0
    {
        int li = lint[gpath][0];
        uint2 v; v.x = 0u; v.y = 0u;
        if (li >= 0) v = *(const uint2*)(ls16 + (size_t)li * 64 + gseg * 4);
        *(uint2*)(&xt[0][gpath * 72 + gseg * 4]) = v;
    }
    __syncthreads();

#pragma unroll 2
    for (int t = 0; t < T_N; ++t) {
        const int cur = t & 1, nxt = (t + 1) & 1;
        bf8_t xA0 = *(const bf8_t*)(&xt[cur][col * 72 + quad * 8]);
        bf8_t xA1 = *(const bf8_t*)(&xt[cur][col * 72 + 32 + quad * 8]);
        bf8_t hA0 = *(const bf8_t*)(&ht[cur][col * 72 + quad * 8]);
        bf8_t hA1 = *(const bf8_t*)(&ht[cur][col * 72 + 32 + quad * 8]);

        // pss row t (cooperative, masked by valid(t-1); row 0 unmasked)
        // ternary (not bitwise |) — avoids compile-time gm>>-1 poison at t==0
        {
            uint2 hv = *(const uint2*)(&ht[cur][gpath * 72 + gseg * 4]);
            int keep = (t == 0) ? 1 : (int)((gm >> (t - 1)) & 1);
            if (!keep) { hv.x = 0u; hv.y = 0u; }
            *(uint2*)(pss + (size_t)(p0 + gpath) * 576 + t * 64 + gseg * 4) = hv;
        }
        // prefetch x_{t+1}
        uint2 pf; pf.x = 0u; pf.y = 0u;
        if (t < T_N - 1) {
            int li = lint[gpath][t + 1];
            if (li >= 0) pf = *(const uint2*)(ls16 + (size_t)li * 64 + gseg * 4);
        }

        f4_t aR = {bR, bR, bR, bR};
        f4_t aZ = {bZ, bZ, bZ, bZ};
        f4_t aI = {bIN, bIN, bIN, bIN};
        f4_t aH = {bHN, bHN, bHN, bHN};
        aR = MFMA16(xA0, BIr[0], aR); aR = MFMA16(xA1, BIr[1], aR);
        aR = MFMA16(hA0, BHr[0], aR); aR = MFMA16(hA1, BHr[1], aR);
        aZ = MFMA16(xA0, BIz[0], aZ); aZ = MFMA16(xA1, BIz[1], aZ);
        aZ = MFMA16(hA0, BHz[0], aZ); aZ = MFMA16(hA1, BHz[1], aZ);
        aI = MFMA16(xA0, BIn[0], aI); aI = MFMA16(xA1, BIn[1], aI);
        aH = MFMA16(hA0, BHn[0], aH); aH = MFMA16(hA1, BHn[1], aH);

        if (t < T_N - 1)
            *(uint2*)(&xt[nxt][gpath * 72 + gseg * 4]) = pf;

        // gate math: 4 values/lane
#pragma unroll
        for (int r = 0; r < 4; ++r) {
            float rr = fast_sig(aR[r]);
            float zz = fast_sig(aZ[r]);
            float nn = fast_tanh(fmaf(rr, aH[r], aI[r]));
            float hb = hf[r];
            float hv = fmaf(zz, hb - nn, nn);     // (1-z)n + z h
            hf[r] = ((pm[r] >> t) & 1) ? hv : hb;
        }
#pragma unroll
        for (int r = 0; r < 4; ++r)
            ht[nxt][(quad * 4 + r) * 72 + w * 16 + col] = f2bf(hf[r]);
        __syncthreads();
    }

    // epilogue: h8 lives in ht[0]; pss row 8 masked by valid(7)
    {
        uint2 hv = *(const uint2*)(&ht[0][gpath * 72 + gseg * 4]);
        if (!((gm >> 7) & 1)) { hv.x = 0u; hv.y = 0u; }
        *(uint2*)(pss + (size_t)(p0 + gpath) * 576 + 8 * 64 + gseg * 4) = hv;
    }
#pragma unroll
    for (int r = 0; r < 4; ++r)
        path_state[(size_t)(p0 + quad * 4 + r) * 64 + w * 16 + col] = hf[r];
}

// ---- link aggregation (R6 form): one wave per link, serial branchy loop ----
__global__ __launch_bounds__(64) void link_agg_k(
    const int* __restrict__ p2l, const unsigned short* __restrict__ pss,
    unsigned short* __restrict__ agg16)
{
    const int l = blockIdx.x;
    const int lane = threadIdx.x;
    float vmin = INFINITY, vmax = -INFINITY, vsum = 0.0f;
    int cnt = 0;
#pragma unroll 1
    for (int d = 0; d < DEG_N; ++d) {
        int pid = p2l[l * 96 + d * 2];
        int pos = p2l[l * 96 + d * 2 + 1];
        if (pid >= 0) {
            float v = bf2f(pss[((size_t)pid * 9 + pos) * 64 + lane]);
            vmin = fminf(vmin, v); vmax = fmaxf(vmax, v); vsum += v; cnt++;
        }
    }
    float mean = vsum / (float)max(cnt, 1);
    unsigned short* row = agg16 + (size_t)l * 512;
    float vals[4] = {vmin, vmax, vsum, mean};
#pragma unroll
    for (int c = 0; c < 4; ++c) {
        unsigned short hi = f2bf(vals[c]);
        row[c * 64 + lane] = hi;
        row[256 + c * 64 + lane] = f2bf(vals[c] - bf2f(hi));
    }
}

// ---- MFMA link update, hi/lo compensated: MLP(256->128->128->64) + GRU cell ----
__global__ __launch_bounds__(256, 2) void link_upd_mfma_k(
    const unsigned short* __restrict__ lw,
    const float* __restrict__ b1, const float* __restrict__ b2, const float* __restrict__ b3,
    const float* __restrict__ cbih, const float* __restrict__ cbhh,
    const unsigned short* __restrict__ agg16,
    float* __restrict__ link_state,
    unsigned short* __restrict__ lshi, unsigned short* __restrict__ lslo)
{
    __shared__ __align__(16) unsigned short tile[4][2 * 16 * 136];
    const int tid = threadIdx.x;
    const int wv = tid >> 6;
    const int L = tid & 63;
    const int col = L & 15;
    const int quad = L >> 4;
    const int l0 = blockIdx.x * 64 + wv * 16;
    const int mlink = min(l0 + col, L_N - 1);
    unsigned short* tlhi = &tile[wv][0];
    unsigned short* tllo = &tile[wv][16 * 136];

    const unsigned short* w1b = lw;            // [128][256]
    const unsigned short* w2b = lw + 32768;    // [128][128]
    const unsigned short* w3b = lw + 49152;    // [64][128]
    const unsigned short* cih = lw + 57344;    // [192][64]
    const unsigned short* chh = lw + 69632;    // [192][64]

    // phase 1
    {
        bf8_t Ah[8], Al[8];
#pragma unroll
        for (int f = 0; f < 8; ++f) {
            Ah[f] = *(const bf8_t*)(agg16 + (size_t)mlink * 512 + f * 32 + quad * 8);
            Al[f] = *(const bf8_t*)(agg16 + (size_t)mlink * 512 + 256 + f * 32 + quad * 8);
        }
#pragma unroll
        for (int nt = 0; nt < 8; ++nt) {
            float bb = b1[nt * 16 + col];
            f4_t acc = {bb, bb, bb, bb};
#pragma unroll
            for (int f = 0; f < 8; ++f) {
                size_t o = (size_t)(nt * 16 + col) * 256 + f * 32 + quad * 8;
                bf8_t Bh = *(const bf8_t*)(w1b + o);
                bf8_t Bl = *(const bf8_t*)(w1b + LWLO + o);
                acc = MFMA16(Ah[f], Bh, acc);
                acc = MFMA16(Ah[f], Bl, acc);
                acc = MFMA16(Al[f], Bh, acc);
            }
#pragma unroll
            for (int r = 0; r < 4; ++r) {
                float v = fmaxf(acc[r], 0.0f);
                unsigned short hi = f2bf(v);
                tlhi[(quad * 4 + r) * 136 + nt * 16 + col] = hi;
                tllo[(quad * 4 + r) * 136 + nt * 16 + col] = f2bf(v - bf2f(hi));
            }
        }
    }
    // phase 2
    {
        bf8_t Ah[4], Al[4];
#pragma unroll
        for (int f = 0; f < 4; ++f) {
            Ah[f] = *(const bf8_t*)(tlhi + col * 136 + f * 32 + quad * 8);
            Al[f] = *(const bf8_t*)(tllo + col * 136 + f * 32 + quad * 8);
        }
        float vv[8][4];
#pragma unroll
        for (int nt = 0; nt < 8; ++nt) {
            float bb = b2[nt * 16 + col];
            f4_t acc = {bb, bb, bb, bb};
#pragma unroll
            for (int f = 0; f < 4; ++f) {
                size_t o = (size_t)(nt * 16 + col) * 128 + f * 32 + quad * 8;
                bf8_t Bh = *(const bf8_t*)(w2b + o);
                bf8_t Bl = *(const bf8_t*)(w2b + LWLO + o);
                acc = MFMA16(Ah[f], Bh, acc);
                acc = MFMA16(Ah[f], Bl, acc);
                acc = MFMA16(Al[f], Bh, acc);
            }
#pragma unroll
            for (int r = 0; r < 4; ++r) vv[nt][r] = fmaxf(acc[r], 0.0f);
        }
#pragma unroll
        for (int nt = 0; nt < 8; ++nt)
#pragma unroll
            for (int r = 0; r < 4; ++r) {
                unsigned short hi = f2bf(vv[nt][r]);
                tlhi[(quad * 4 + r) * 136 + nt * 16 + col] = hi;
                tllo[(quad * 4 + r) * 136 + nt * 16 + col] = f2bf(vv[nt][r] - bf2f(hi));
            }
    }
    // phase 3
    {
        bf8_t Ah[4], Al[4];
#pragma unroll
        for (int f = 0; f < 4; ++f) {
            Ah[f] = *(const bf8_t*)(tlhi + col * 136 + f * 32 + quad * 8);
            Al[f] = *(const bf8_t*)(tllo + col * 136 + f * 32 + quad * 8);
        }
        float vv[4][4];
#pragma unroll
        for (int nt = 0; nt < 4; ++nt) {
            float bb = b3[nt * 16 + col];
            f4_t acc = {bb, bb, bb, bb};
#pragma unroll
            for (int f = 0; f < 4; ++f) {
                size_t o = (size_t)(nt * 16 + col) * 128 + f * 32 + quad * 8;
                bf8_t Bh = *(const bf8_t*)(w3b + o);
                bf8_t Bl = *(const bf8_t*)(w3b + LWLO + o);
                acc = MFMA16(Ah[f], Bh, acc);
                acc = MFMA16(Ah[f], Bl, acc);
                acc = MFMA16(Al[f], Bh, acc);
            }
#pragma unroll
            for (int r = 0; r < 4; ++r) vv[nt][r] = fmaxf(acc[r], 0.0f);
        }
#pragma unroll
        for (int nt = 0; nt < 4; ++nt)
#pragma unroll
            for (int r = 0; r < 4; ++r) {
                unsigned short hi = f2bf(vv[nt][r]);
                tlhi[(quad * 4 + r) * 136 + nt * 16 + col] = hi;
                tllo[(quad * 4 + r) * 136 + nt * 16 + col] = f2bf(vv[nt][r] - bf2f(hi));
            }
    }
    // GRU cell
    bf8_t xAh[2], xAl[2], hAh[2], hAl[2];
#pragma unroll
    for (int f = 0; f < 2; ++f) {
        xAh[f] = *(const bf8_t*)(tlhi + col * 136 + f * 32 + quad * 8);
        xAl[f] = *(const bf8_t*)(tllo + col * 136 + f * 32 + quad * 8);
        hAh[f] = *(const bf8_t*)(lshi + (size_t)mlink * 64 + f * 32 + quad * 8);
        hAl[f] = *(const bf8_t*)(lslo + (size_t)mlink * 64 + f * 32 + quad * 8);
    }
    float hf[16];
#pragma unroll
    for (int nt = 0; nt < 4; ++nt)
#pragma unroll
        for (int r = 0; r < 4; ++r) {
            int ml = min(l0 + quad * 4 + r, L_N - 1);
            hf[nt * 4 + r] = link_state[(size_t)ml * 64 + nt * 16 + col];
        }
    f4_t aRZ[8], aIN[4], aHN[4];
#pragma unroll
    for (int nt = 0; nt < 8; ++nt) {
        float bb = cbih[nt * 16 + col] + cbhh[nt * 16 + col];
        aRZ[nt][0] = bb; aRZ[nt][1] = bb; aRZ[nt][2] = bb; aRZ[nt][3] = bb;
    }
#pragma unroll
    for (int nt = 0; nt < 4; ++nt) {
        float bi = cbih[128 + nt * 16 + col], bh = cbhh[128 + nt * 16 + col];
        aIN[nt][0] = bi; aIN[nt][1] = bi; aIN[nt][2] = bi; aIN[nt][3] = bi;
        aHN[nt][0] = bh; aHN[nt][1] = bh; aHN[nt][2] = bh; aHN[nt][3] = bh;
    }
#pragma unroll
    for (int nt = 0; nt < 8; ++nt) {
#pragma unroll
        for (int f = 0; f < 2; ++f) {
            size_t o = (size_t)(nt * 16 + col) * 64 + f * 32 + quad * 8;
            bf8_t Bih = *(const bf8_t*)(cih + o);
            bf8_t Bil = *(const bf8_t*)(cih + LWLO + o);
            bf8_t Bhh = *(const bf8_t*)(chh + o);
            bf8_t Bhl = *(const bf8_t*)(chh + LWLO + o);
            aRZ[nt] = MFMA16(xAh[f], Bih, aRZ[nt]);
            aRZ[nt] = MFMA16(xAh[f], Bil, aRZ[nt]);
            aRZ[nt] = MFMA16(xAl[f], Bih, aRZ[nt]);
            aRZ[nt] = MFMA16(hAh[f], Bhh, aRZ[nt]);
            aRZ[nt] = MFMA16(hAh[f], Bhl, aRZ[nt]);
            aRZ[nt] = MFMA16(hAl[f], Bhh, aRZ[nt]);
        }
    }
#pragma unroll
    for (int nt = 0; nt < 4; ++nt) {
#pragma unroll
        for (int f = 0; f < 2; ++f) {
            size_t o = (size_t)((8 + nt) * 16 + col) * 64 + f * 32 + quad * 8;
            bf8_t Bih = *(const bf8_t*)(cih + o);
            bf8_t Bil = *(const bf8_t*)(cih + LWLO + o);
            bf8_t Bhh = *(const bf8_t*)(chh + o);
            bf8_t Bhl = *(const bf8_t*)(chh + LWLO + o);
            aIN[nt] = MFMA16(xAh[f], Bih, aIN[nt]);
            aIN[nt] = MFMA16(xAh[f], Bil, aIN[nt]);
            aIN[nt] = MFMA16(xAl[f], Bih, aIN[nt]);
            aHN[nt] = MFMA16(hAh[f], Bhh, aHN[nt]);
            aHN[nt] = MFMA16(hAh[f], Bhl, aHN[nt]);
            aHN[nt] = MFMA16(hAl[f], Bhh, aHN[nt]);
        }
    }
#pragma unroll
    for (int nt = 0; nt < 4; ++nt)
#pragma unroll
        for (int r = 0; r < 4; ++r) {
            int mrow = l0 + quad * 4 + r;
            float rr = fast_sig(aRZ[nt][r]);
            float zz = fast_sig(aRZ[nt + 4][r]);
            float nn = fast_tanh(fmaf(rr, aHN[nt][r], aIN[nt][r]));
            float hb = hf[nt * 4 + r];
            float hv = fmaf(zz, hb - nn, nn);
            if (mrow < L_N) {
                link_state[(size_t)mrow * 64 + nt * 16 + col] = hv;
                unsigned short hi = f2bf(hv);
                lshi[(size_t)mrow * 64 + nt * 16 + col] = hi;
                lslo[(size_t)mrow * 64 + nt * 16 + col] = f2bf(hv - bf2f(hi));
            }
        }
}

// ---- final fp32 -> (bf16 | f32) output ----
__global__ void final_out_k(const float* __restrict__ ps, const float* __restrict__ ls,
                            void* __restrict__ out, const int* __restrict__ flag)
{
    int i = blockIdx.x * 256 + threadIdx.x;
    int e = i * 2;
    float a, b;
    if (e < P_N * D_N) { a = ps[e]; b = ps[e + 1]; }
    else               { a = ls[e - P_N * D_N]; b = ls[e - P_N * D_N + 1]; }
    if (*flag) {
        ((unsigned*)out)[i] = pk2(a, b);
    } else {
        float2 v; v.x = a; v.y = b;
        ((float2*)out)[i] = v;
    }
}

extern "C" void kernel_launch(void* const* d_in, const int* in_sizes, int n_in,
                              void* d_out, int out_size, void* d_ws, size_t ws_size,
                              hipStream_t stream)
{
    const int* l2p = (const int*)d_in[2];
    const int* p2l = (const int*)d_in[3];
    float* ws = (float*)d_ws;
    int* flag = (int*)(ws + OFF_FLAG);
    unsigned short* wih16 = (unsigned short*)(ws + OFF_WIH16);
    unsigned short* whh16 = (unsigned short*)(ws + OFF_WHH16);
    unsigned short* lshi  = (unsigned short*)(ws + OFF_LS16);
    unsigned short* lslo  = (unsigned short*)(ws + OFF_LSLO);
    unsigned short* lw16  = (unsigned short*)(ws + OFF_LW16);
    unsigned short* agg16 = (unsigned short*)(ws + OFF_AG);
    unsigned short* pss   = (unsigned short*)(ws + OFF_PSS);

    detect_k<<<1, 64, 0, stream>>>((const unsigned short*)d_in[0], flag);

    WSrc srcs;
    for (int i = 0; i < 22; ++i) srcs.p[i] = d_in[4 + i];
    conv_weights_k<<<22, 256, 0, stream>>>(srcs, ws, flag);
    conv_gru16_k<<<48, 256, 0, stream>>>(ws, wih16, whh16);
    conv_link16_k<<<320, 256, 0, stream>>>(ws, lw16);

    embed_k<<<(P_N + 255) / 256, 256, 0, stream>>>(d_in[0], ws + W_PE_W1, ws + W_PE_B1,
                                                   ws + W_PE_W2, ws + W_PE_B2, ws + OFF_PS, P_N, flag);
    embed_k<<<(L_N + 255) / 256, 256, 0, stream>>>(d_in[1], ws + W_LE_W1, ws + W_LE_B1,
                                                   ws + W_LE_W2, ws + W_LE_B2, ws + OFF_LS, L_N, flag);
    ls_to16_k<<<(L_N * D_N + 255) / 256, 256, 0, stream>>>(ws + OFF_LS, lshi, lslo);

    for (int it = 0; it < 4; ++it) {
        path_gru_mfma_k<<<P_N / 16, 256, 0, stream>>>(
            wih16, whh16, ws + W_GRU_BIH, ws + W_GRU_BHH,
            lshi, ws + OFF_PS, l2p, pss);
        link_agg_k<<<L_N, 64, 0, stream>>>(p2l, pss, agg16);
        link_upd_mfma_k<<<(L_N + 63) / 64, 256, 0, stream>>>(
            lw16, ws + W_AM_B1, ws + W_AM_B2, ws + W_AM_B3,
            ws + W_CELL_BIH, ws + W_CELL_BHH,
            agg16, ws + OFF_LS, lshi, lslo);
    }
    final_out_k<<<(P_N * D_N + L_N * D_N) / 512, 256, 0, stream>>>(
        ws + OFF_PS, ws + OFF_LS, d_out, flag);
}